// Round 20
// baseline (117.745 us; speedup 1.0000x reference)
//
#include <hip/hip_runtime.h>
#include <math.h>

#define DEV static __device__ __forceinline__

typedef __attribute__((ext_vector_type(4))) float f32x4;
typedef __attribute__((ext_vector_type(2))) unsigned u32x2;
typedef __attribute__((ext_vector_type(8))) __bf16 bf16x8;
typedef __attribute__((ext_vector_type(8))) unsigned short u16x8;
typedef __attribute__((ext_vector_type(4))) unsigned short u16x4;

constexpr int TB = 2;     // batch
constexpr int TT = 2048;  // seq len
constexpr int DM = 1024;  // model dim
constexpr int NH = 16;    // heads
constexpr int DH = 64;    // head dim
constexpr int MR = TB * TT;  // 4096 rows
constexpr int SQKV = 3 * DM; // fused QKV width

DEV unsigned short f2bf(float f) {
  union { float f; unsigned u; } v; v.f = f;
  return (unsigned short)((v.u + 0x7FFFu + ((v.u >> 16) & 1u)) >> 16);
}

DEV unsigned cvtpk(float a, float b) {  // lo=bf16(a), hi=bf16(b)
  unsigned r;
  asm("v_cvt_pk_bf16_f32 %0, %1, %2" : "=v"(r) : "v"(a), "v"(b));
  return r;
}

DEV void gld16(const void* g, void* l) {
  __builtin_amdgcn_global_load_lds((const __attribute__((address_space(1))) void*)g,
                                   (__attribute__((address_space(3))) void*)l, 16, 0, 0);
}

DEV bf16x8 ldsb8(const unsigned short* p) { return *(const bf16x8*)p; }

// ---------- merged preprocessing: 4 weight transposes + x fp32->bf16 ----------
__global__ __launch_bounds__(256) void k_prep(const float* __restrict__ x,
                                              const float* __restrict__ w0,
                                              const float* __restrict__ w1,
                                              const float* __restrict__ w2,
                                              const float* __restrict__ w3,
                                              unsigned short* __restrict__ xb,
                                              unsigned short* __restrict__ wtdst) {
  __shared__ float tile[32][33];
  const int id = blockIdx.x, tid = threadIdx.x;
  if (id < 4096) {
    const int z = id >> 10, tl = id & 1023;
    const float* w = z == 0 ? w0 : z == 1 ? w1 : z == 2 ? w2 : w3;
    unsigned short* wt = wtdst + (size_t)z * DM * DM;
    const int n0 = (tl & 31) * 32, k0 = (tl >> 5) * 32;
    const int tx = tid & 31, ty = tid >> 5;  // 32 x 8
#pragma unroll
    for (int yy = 0; yy < 32; yy += 8)
      tile[ty + yy][tx] = w[(size_t)(k0 + ty + yy) * DM + n0 + tx];
    __syncthreads();
#pragma unroll
    for (int yy = 0; yy < 32; yy += 8)
      wt[(size_t)(n0 + ty + yy) * DM + k0 + tx] = f2bf(tile[tx][ty + yy]);
  } else {
    const int i = ((id - 4096) * 256 + tid) * 8;
    f32x4 a = *(const f32x4*)(x + i);
    f32x4 b = *(const f32x4*)(x + i + 4);
    u16x8 o;
#pragma unroll
    for (int j = 0; j < 4; ++j) { o[j] = f2bf(a[j]); o[j + 4] = f2bf(b[j]); }
    *(u16x8*)(xb + i) = o;
  }
}

// ---------- QKV GEMM (R17 best): 8 waves, triple-buffered depth-2 vmcnt(2) ----------
__global__ __launch_bounds__(512) void k_gemm_qkv(const unsigned short* __restrict__ A,
                                                  const unsigned short* __restrict__ Bt,
                                                  unsigned short* __restrict__ Qb,
                                                  float ascale,
                                                  unsigned short* __restrict__ kp,
                                                  unsigned short* __restrict__ vt) {
  constexpr int K = DM, NS = K / 32;
  __shared__ alignas(16) unsigned short As[3][128 * 32];
  __shared__ alignas(16) unsigned short Bs[3][128 * 32];
  const int tid = threadIdx.x;
  const int m0 = blockIdx.y * 128, n0 = blockIdx.x * 128;
  const int lane = tid & 63, w = tid >> 6;
  const int lr = lane & 15, lg = lane >> 4;
  const int wm = w >> 2, wn = w & 3;  // 2 x 4 waves; per-wave region 64 x 32
  const int srow = tid >> 2, scc = (tid & 3) ^ ((srow >> 1) & 3);
  const unsigned short* Ab = A + (size_t)(m0 + srow) * K + scc * 8;
  const unsigned short* Bb = Bt + (size_t)(n0 + srow) * K + scc * 8;
  auto stage = [&](int buf, int s) {  // exactly 2 loads per thread
    gld16(Ab + s * 32, (void*)(As[buf] + tid * 8));
    gld16(Bb + s * 32, (void*)(Bs[buf] + tid * 8));
  };
  f32x4 acc[4][2] = {};
  stage(0, 0);
  stage(1, 1);
  int buf = 0;
  for (int s = 0; s < NS; ++s) {
    if (s + 1 < NS) {
      asm volatile("s_waitcnt vmcnt(2)" ::: "memory");  // tile s landed; s+1 in flight
    } else {
      asm volatile("s_waitcnt vmcnt(0)" ::: "memory");
    }
    __builtin_amdgcn_s_barrier();
    if (s + 2 < NS) {
      int nb = buf + 2; if (nb >= 3) nb -= 3;
      stage(nb, s + 2);  // overwrites buf read at s-1: sealed by barrier(s)
    }
    bf16x8 af[4], bfr[2];
#pragma unroll
    for (int i = 0; i < 4; ++i) {
      const int row = wm * 64 + i * 16 + lr;
      af[i] = ldsb8(As[buf] + row * 32 + ((lg ^ ((row >> 1) & 3)) * 8));
    }
#pragma unroll
    for (int j = 0; j < 2; ++j) {
      const int row = wn * 32 + j * 16 + lr;
      bfr[j] = ldsb8(Bs[buf] + row * 32 + ((lg ^ ((row >> 1) & 3)) * 8));
    }
    __builtin_amdgcn_s_setprio(1);
#pragma unroll
    for (int i = 0; i < 4; ++i)
#pragma unroll
      for (int j = 0; j < 2; ++j)
        acc[i][j] = __builtin_amdgcn_mfma_f32_16x16x32_bf16(af[i], bfr[j], acc[i][j], 0, 0, 0);
    __builtin_amdgcn_s_setprio(0);
    if (++buf >= 3) buf = 0;
  }
#pragma unroll
  for (int i = 0; i < 4; ++i)
#pragma unroll
    for (int j = 0; j < 2; ++j) {
      const int row = m0 + wm * 64 + i * 16 + lg * 4;
      const int col = n0 + wn * 32 + j * 16 + lr;
      const int bb = row >> 11, sg = row & (TT - 1);
      if (col < DM) {  // Q (pre-scaled)
#pragma unroll
        for (int r = 0; r < 4; ++r)
          Qb[(size_t)(row + r) * DM + col] = f2bf(acc[i][j][r] * ascale);
      } else if (col < 2 * DM) {  // K -> packed swizzled tiles
        const int hh = (col - DM) >> 6, dd = (col - DM) & 63;
        unsigned short* kb = kp + (size_t)(bb * NH + hh) * 32 * 4096;
#pragma unroll
        for (int r = 0; r < 4; ++r) {
          const int s = sg + r, t = s >> 6, sl = s & 63;
          kb[t * 4096 + sl * 64 + (((dd >> 3) ^ (sl & 7)) * 8) + (dd & 7)] = f2bf(acc[i][j][r]);
        }
      } else {  // V -> PV-native tiles
        const int hh = (col - 2 * DM) >> 6, dd = (col - 2 * DM) & 63;
        const int t = sg >> 6, sl = sg & 63;
        const int g = ((sl >> 5) << 2) | ((sl >> 2) & 3);
        const int hf2 = (sl >> 4) & 1;
        const int cch = g ^ (dd & 7);
        u16x4 pk;
#pragma unroll
        for (int r = 0; r < 4; ++r) pk[r] = f2bf(acc[i][j][r]);
        *(u16x4*)(vt + (size_t)((bb * NH + hh) * 32 + t) * 4096 + dd * 64 + cch * 8 + hf2 * 4) = pk;
      }
    }
}

// ---------- out-proj GEMM with FUSED norm for split rows ----------
// Blocks with (m0 & 1024) are entirely split-class (q>=1024): A staged by
// reg-loading fp32 partials, (a0+a1)/l -> bf16 -> ds_write to the SAME
// swizzled LDS slot gld16 would fill. Whole-class blocks: R17 counted pipeline.
__global__ __launch_bounds__(512) void k_gemm_out(const unsigned short* __restrict__ A,
                                                  const unsigned short* __restrict__ Bt,
                                                  const float* __restrict__ Oacc0,
                                                  const float* __restrict__ Oacc1,
                                                  const float* __restrict__ lacc0,
                                                  const float* __restrict__ lacc1,
                                                  float* __restrict__ C) {
  constexpr int K = DM, N = DM, NS = K / 32;
  __shared__ alignas(16) unsigned short As[3][128 * 32];
  __shared__ alignas(16) unsigned short Bs[3][64 * 32];
  const int tid = threadIdx.x;
  const int m0 = blockIdx.y * 128, n0 = blockIdx.x * 64;
  const int lane = tid & 63, w = tid >> 6;
  const int lr = lane & 15, lg = lane >> 4;
  const int wm = w >> 1, wn = w & 1;
  const int srow = tid >> 2, scc = (tid & 3) ^ ((srow >> 1) & 3);
  const unsigned short* Ab = A + (size_t)(m0 + srow) * K + scc * 8;
  const unsigned short* Bb = (tid < 256) ? Bt + (size_t)(n0 + srow) * K + scc * 8 : nullptr;
  f32x4 acc[2][2] = {};
  const bool splitBlk = (m0 & 1024) != 0;

  if (!splitBlk) {
    // ---- whole-class: R17 triple-buffered counted-vmcnt pipeline ----
    auto stage = [&](int buf, int s) {
      gld16(Ab + s * 32, (void*)(As[buf] + tid * 8));
      if (tid < 256) gld16(Bb + s * 32, (void*)(Bs[buf] + tid * 8));
    };
    stage(0, 0);
    stage(1, 1);
    int buf = 0;
    for (int s = 0; s < NS; ++s) {
      if (s + 1 < NS) {
        if (w < 4) {
          asm volatile("s_waitcnt vmcnt(2)" ::: "memory");
        } else {
          asm volatile("s_waitcnt vmcnt(1)" ::: "memory");
        }
      } else {
        asm volatile("s_waitcnt vmcnt(0)" ::: "memory");
      }
      __builtin_amdgcn_s_barrier();
      if (s + 2 < NS) {
        int nb = buf + 2; if (nb >= 3) nb -= 3;
        stage(nb, s + 2);
      }
      bf16x8 af[2], bfr[2];
#pragma unroll
      for (int i = 0; i < 2; ++i) {
        const int row = wm * 32 + i * 16 + lr;
        af[i] = ldsb8(As[buf] + row * 32 + ((lg ^ ((row >> 1) & 3)) * 8));
      }
#pragma unroll
      for (int j = 0; j < 2; ++j) {
        const int row = wn * 32 + j * 16 + lr;
        bfr[j] = ldsb8(Bs[buf] + row * 32 + ((lg ^ ((row >> 1) & 3)) * 8));
      }
      __builtin_amdgcn_s_setprio(1);
#pragma unroll
      for (int i = 0; i < 2; ++i)
#pragma unroll
        for (int j = 0; j < 2; ++j)
          acc[i][j] = __builtin_amdgcn_mfma_f32_16x16x32_bf16(af[i], bfr[j], acc[i][j], 0, 0, 0);
      __builtin_amdgcn_s_setprio(0);
      if (++buf >= 3) buf = 0;
    }
  } else {
    // ---- split-class: fused (Oacc0+Oacc1)/l on the A-path, double-buffered ----
    const int b_ = (m0 + srow) >> 11;
    const int jj = (m0 >> 7) & 7;  // (q-1024)>>7, constant per block
    f32x4 ra0, ra1, rb0, rb1;
    float rl;
    auto issueA = [&](int s) {
      const int h2 = s >> 1;
      const size_t ri = (size_t)((b_ * NH + h2) * 8 + jj) * 128 + srow;
      const size_t base = ri * 64 + (s & 1) * 32 + scc * 8;
      ra0 = *(const f32x4*)(Oacc0 + base);
      ra1 = *(const f32x4*)(Oacc0 + base + 4);
      rb0 = *(const f32x4*)(Oacc1 + base);
      rb1 = *(const f32x4*)(Oacc1 + base + 4);
      rl = lacc0[ri] + lacc1[ri];
    };
    issueA(0);
    if (tid < 256) gld16(Bb, (void*)(Bs[0] + tid * 8));
    for (int s = 0; s < NS; ++s) {
      const int buf = s & 1;
      // convert+write A(s) from regs (compiler inserts waits on ra/rb/rl)
      const float linv = 1.f / rl;
      u16x8 aw;
#pragma unroll
      for (int q = 0; q < 4; ++q) {
        aw[q] = f2bf((ra0[q] + rb0[q]) * linv);
        aw[q + 4] = f2bf((ra1[q] + rb1[q]) * linv);
      }
      *(u16x8*)(As[buf] + tid * 8) = aw;
      asm volatile("s_waitcnt vmcnt(0)" ::: "memory");  // B(s) landed in LDS
      __syncthreads();  // A ds_write visible; all waves done with buf^1
      if (s + 1 < NS) {
        issueA(s + 1);  // regs: fly under compute(s)
        if (tid < 256) gld16(Bb + (s + 1) * 32, (void*)(Bs[buf ^ 1] + tid * 8));
      }
      bf16x8 af[2], bfr[2];
#pragma unroll
      for (int i = 0; i < 2; ++i) {
        const int row = wm * 32 + i * 16 + lr;
        af[i] = ldsb8(As[buf] + row * 32 + ((lg ^ ((row >> 1) & 3)) * 8));
      }
#pragma unroll
      for (int j = 0; j < 2; ++j) {
        const int row = wn * 32 + j * 16 + lr;
        bfr[j] = ldsb8(Bs[buf] + row * 32 + ((lg ^ ((row >> 1) & 3)) * 8));
      }
      __builtin_amdgcn_s_setprio(1);
#pragma unroll
      for (int i = 0; i < 2; ++i)
#pragma unroll
        for (int j = 0; j < 2; ++j)
          acc[i][j] = __builtin_amdgcn_mfma_f32_16x16x32_bf16(af[i], bfr[j], acc[i][j], 0, 0, 0);
      __builtin_amdgcn_s_setprio(0);
      __syncthreads();  // protect buf before next iter's A ds_write overwrites it
    }
  }
#pragma unroll
  for (int i = 0; i < 2; ++i)
#pragma unroll
    for (int j = 0; j < 2; ++j) {
      const int row = m0 + wm * 32 + i * 16 + lg * 4;
      const int col = n0 + wn * 32 + j * 16 + lr;
#pragma unroll
      for (int r = 0; r < 4; ++r) C[(size_t)(row + r) * N + col] = acc[i][j][r];
    }
}

// ---------- causal flash attention v15 (R16 best): split-K triple-buffer + MFMA row-sum ----------
__constant__ const signed char JV[24]  = {15,7,14,14,13,13,12,11, 15,6,12,10,10,9,11,5, 0,1,2,3,8,4,8,9};
__constant__ const signed char T0v[24] = {0,0,0,15,0,14,13,12, 16,0,0,0,11,0,0,0, 0,0,0,0,0,0,9,10};
__constant__ const signed char CNTv[24]= {16,16,15,15,14,14,13,12, 16,14,13,11,11,10,12,12, 2,4,6,8,9,10,9,10};

__global__ __launch_bounds__(512) void k_attn15(const unsigned short* __restrict__ Qb,
                                                const unsigned short* __restrict__ Kp,
                                                const unsigned short* __restrict__ Vt,
                                                unsigned short* __restrict__ O,
                                                float* __restrict__ Oacc0,
                                                float* __restrict__ Oacc1,
                                                float* __restrict__ lacc0,
                                                float* __restrict__ lacc1) {
  __shared__ alignas(16) unsigned short Ks[3][64 * 64];
  __shared__ alignas(16) unsigned short Vs[3][64 * 64];
  const int id = blockIdx.x;
  const int rank = id >> 5, bh = id & 31;
  const int j = JV[rank], t0 = T0v[rank], cnt = CNTv[rank];
  const bool split = (j >= 8);
  const int hf = (t0 > 0) ? 1 : 0;
  const int b = bh >> 4, h = bh & 15;
  const int q0 = j * 128;
  const int tid = threadIdx.x, lane = tid & 63, w = tid >> 6;
  const int lr = lane & 15, lg = lane >> 4;
  const int lsw = lr & 7;
  const int qw = q0 + w * 16;
  const unsigned short* Qg = Qb + (size_t)b * TT * DM + h * DH;
  const unsigned short* kbase = Kp + (size_t)bh * 32 * 4096 + tid * 8;
  const unsigned short* vbase = Vt + (size_t)bh * 32 * 4096 + tid * 8;

  bf16x8 qf[2];
#pragma unroll
  for (int c2 = 0; c2 < 2; ++c2)
    qf[c2] = *(const bf16x8*)(Qg + (size_t)(qw + lr) * DM + c2 * 32 + lg * 8);

  bf16x8 onef;
  {
    union { unsigned short s[8]; bf16x8 v; } ou;
#pragma unroll
    for (int i = 0; i < 8; ++i) ou.s[i] = 0x3F80;
    onef = ou.v;
  }

  f32x4 acco[4] = {};
  f32x4 lac = {};

  auto stage = [&](int buf, int t) {
    gld16(kbase + (size_t)t * 4096, (void*)(Ks[buf] + tid * 8));
    gld16(vbase + (size_t)t * 4096, (void*)(Vs[buf] + tid * 8));
  };

  stage(0, t0);
  stage(1, t0 + 1);  // cnt >= 2 always
  int buf = 0;
  for (int k = 0; k < cnt; ++k) {
    const int t = t0 + k;
    if (k + 1 < cnt) {
      asm volatile("s_waitcnt vmcnt(2)" ::: "memory");
    } else {
      asm volatile("s_waitcnt vmcnt(0)" ::: "memory");
    }
    __builtin_amdgcn_s_barrier();
    if (k + 2 < cnt) {
      int nb = buf + 2; if (nb >= 3) nb -= 3;
      stage(nb, t + 2);
    }
    const int s0 = t * 64;
    if (s0 <= qw + 15) {
      const unsigned short* Kb_ = Ks[buf];
      const unsigned short* Vb_ = Vs[buf];
      f32x4 st[4] = {};
      __builtin_amdgcn_s_setprio(1);
#pragma unroll
      for (int ct = 0; ct < 4; ++ct)
#pragma unroll
        for (int c2 = 0; c2 < 2; ++c2) {
          bf16x8 kf = ldsb8(Kb_ + (ct * 16 + lr) * 64 + (((c2 * 4 + lg) ^ lsw) * 8));
          st[ct] = __builtin_amdgcn_mfma_f32_16x16x32_bf16(kf, qf[c2], st[ct], 0, 0, 0);
        }
      __builtin_amdgcn_s_setprio(0);
      float p[4][4];
      const int qrel = qw + lr - s0;
      if (s0 + 63 >= qw) {
#pragma unroll
        for (int ct = 0; ct < 4; ++ct)
#pragma unroll
          for (int r = 0; r < 4; ++r) {
            float v = st[ct][r];
            if (ct * 16 + lg * 4 + r > qrel) v = -1e30f;
            p[ct][r] = v;
          }
      } else {
#pragma unroll
        for (int ct = 0; ct < 4; ++ct)
#pragma unroll
          for (int r = 0; r < 4; ++r) p[ct][r] = st[ct][r];
      }
#pragma unroll
      for (int ct = 0; ct < 4; ++ct)
#pragma unroll
        for (int r = 0; r < 4; ++r) p[ct][r] = __builtin_exp2f(p[ct][r]);
      bf16x8 pf[2];
#pragma unroll
      for (int ks = 0; ks < 2; ++ks) {
        union { unsigned w4[4]; bf16x8 v; } pu;
        pu.w4[0] = cvtpk(p[2 * ks][0], p[2 * ks][1]);
        pu.w4[1] = cvtpk(p[2 * ks][2], p[2 * ks][3]);
        pu.w4[2] = cvtpk(p[2 * ks + 1][0], p[2 * ks + 1][1]);
        pu.w4[3] = cvtpk(p[2 * ks + 1][2], p[2 * ks + 1][3]);
        pf[ks] = pu.v;
      }
      __builtin_amdgcn_s_setprio(1);
#pragma unroll
      for (int dt = 0; dt < 4; ++dt) {
        const unsigned short* Vrow = Vb_ + (dt * 16 + lr) * 64;
#pragma unroll
        for (int ks = 0; ks < 2; ++ks) {
          bf16x8 vf = ldsb8(Vrow + (((ks * 4 + lg) ^ lsw) * 8));
          acco[dt] = __builtin_amdgcn_mfma_f32_16x16x32_bf16(pf[ks], vf, acco[dt], 0, 0, 0);
        }
      }
#pragma unroll
      for (int ks = 0; ks < 2; ++ks)
        lac = __builtin_amdgcn_mfma_f32_16x16x32_bf16(pf[ks], onef, lac, 0, 0, 0);
      __builtin_amdgcn_s_setprio(0);
    }
    if (++buf >= 3) buf = 0;
  }
  if (!split) {
#pragma unroll
    for (int r = 0; r < 4; ++r) {
      const float linv = 1.f / lac[r];
      const int q = qw + lg * 4 + r;
#pragma unroll
      for (int dt = 0; dt < 4; ++dt)
        O[(size_t)(b * TT + q) * DM + h * DH + dt * 16 + lr] = f2bf(acco[dt][r] * linv);
    }
  } else {
    const int jj = j - 8;
    float* Oa = (hf ? Oacc1 : Oacc0) + (size_t)(bh * 8 + jj) * 128 * 64;
    float* la = (hf ? lacc1 : lacc0) + (size_t)(bh * 8 + jj) * 128;
#pragma unroll
    for (int dt = 0; dt < 4; ++dt)
#pragma unroll
      for (int r = 0; r < 4; ++r)
        Oa[(w * 16 + lg * 4 + r) * 64 + dt * 16 + lr] = acco[dt][r];
    if (lr == 0) {
#pragma unroll
      for (int r = 0; r < 4; ++r) la[w * 16 + lg * 4 + r] = lac[r];
    }
  }
}

extern "C" void kernel_launch(void* const* d_in, const int* in_sizes, int n_in,
                              void* d_out, int out_size, void* d_ws, size_t ws_size,
                              hipStream_t stream) {
  const float* x = (const float*)d_in[0];
  const float* wq = (const float*)d_in[1];
  const float* wk = (const float*)d_in[2];
  const float* wv = (const float*)d_in[3];
  const float* wo = (const float*)d_in[4];
  float* out = (float*)d_out;
  char* ws = (char*)d_ws;
  const size_t MB = 1u << 20;
  // ws layout (48 MB), lifetime-disjoint reuse:
  unsigned short* xb = (unsigned short*)(ws);              // 8MB: x bf16 (dead after qkv)
  float* Oacc0 = (float*)(ws);                             //  ... reused: fp32 O partials h=0
  unsigned short* wqt = (unsigned short*)(ws + 8 * MB);    // 8MB: 4 transposed weights
  float* lacc0 = (float*)(ws + 8 * MB);                    //  ... wq^T dead after qkv: l partials
  float* lacc1 = (float*)(ws + 8 * MB + (32 * 8 * 128) * 4);
  unsigned short* wot = (unsigned short*)(ws + 14 * MB);   // wo^T (live until out-proj)
  unsigned short* Qb = (unsigned short*)(ws + 16 * MB);    // 8MB: Q; reused as attn-out
  unsigned short* Kp = (unsigned short*)(ws + 24 * MB);    // 8MB: packed swizzled K tiles
  unsigned short* Vtb = (unsigned short*)(ws + 32 * MB);   // 8MB: PV-native V tiles
  float* Oacc1 = (float*)(ws + 40 * MB);                   // 8MB: fp32 O partials h=1

  k_prep<<<dim3(6144), 256, 0, stream>>>(x, wq, wk, wv, wo, xb, wqt);
  k_gemm_qkv<<<dim3(24, 32), 512, 0, stream>>>(xb, wqt, Qb, 0.18033688f, Kp, Vtb);
  k_attn15<<<dim3(768), 512, 0, stream>>>(Qb, Kp, Vtb, Qb, Oacc0, Oacc1, lacc0, lacc1);
  k_gemm_out<<<dim3(16, 32), 512, 0, stream>>>(Qb, wot, Oacc0, Oacc1, lacc0, lacc1, out);
}

// Round 21
// 104.729 us; speedup vs baseline: 1.1243x; 1.1243x over previous
//
#include <hip/hip_runtime.h>
#include <math.h>

#define DEV static __device__ __forceinline__

typedef __attribute__((ext_vector_type(4))) float f32x4;
typedef __attribute__((ext_vector_type(2))) unsigned u32x2;
typedef __attribute__((ext_vector_type(8))) __bf16 bf16x8;
typedef __attribute__((ext_vector_type(8))) unsigned short u16x8;
typedef __attribute__((ext_vector_type(4))) unsigned short u16x4;

constexpr int TB = 2;     // batch
constexpr int TT = 2048;  // seq len
constexpr int DM = 1024;  // model dim
constexpr int NH = 16;    // heads
constexpr int DH = 64;    // head dim
constexpr int MR = TB * TT;  // 4096 rows
constexpr int SQKV = 3 * DM; // fused QKV width

DEV unsigned short f2bf(float f) {
  union { float f; unsigned u; } v; v.f = f;
  return (unsigned short)((v.u + 0x7FFFu + ((v.u >> 16) & 1u)) >> 16);
}

DEV unsigned cvtpk(float a, float b) {  // lo=bf16(a), hi=bf16(b)
  unsigned r;
  asm("v_cvt_pk_bf16_f32 %0, %1, %2" : "=v"(r) : "v"(a), "v"(b));
  return r;
}

DEV void gld16(const void* g, void* l) {
  __builtin_amdgcn_global_load_lds((const __attribute__((address_space(1))) void*)g,
                                   (__attribute__((address_space(3))) void*)l, 16, 0, 0);
}

DEV bf16x8 ldsb8(const unsigned short* p) { return *(const bf16x8*)p; }

// ---------- merged preprocessing: 4 weight transposes + x fp32->bf16 ----------
__global__ __launch_bounds__(256) void k_prep(const float* __restrict__ x,
                                              const float* __restrict__ w0,
                                              const float* __restrict__ w1,
                                              const float* __restrict__ w2,
                                              const float* __restrict__ w3,
                                              unsigned short* __restrict__ xb,
                                              unsigned short* __restrict__ wtdst) {
  __shared__ float tile[32][33];
  const int id = blockIdx.x, tid = threadIdx.x;
  if (id < 4096) {
    const int z = id >> 10, tl = id & 1023;
    const float* w = z == 0 ? w0 : z == 1 ? w1 : z == 2 ? w2 : w3;
    unsigned short* wt = wtdst + (size_t)z * DM * DM;
    const int n0 = (tl & 31) * 32, k0 = (tl >> 5) * 32;
    const int tx = tid & 31, ty = tid >> 5;  // 32 x 8
#pragma unroll
    for (int yy = 0; yy < 32; yy += 8)
      tile[ty + yy][tx] = w[(size_t)(k0 + ty + yy) * DM + n0 + tx];
    __syncthreads();
#pragma unroll
    for (int yy = 0; yy < 32; yy += 8)
      wt[(size_t)(n0 + ty + yy) * DM + k0 + tx] = f2bf(tile[tx][ty + yy]);
  } else {
    const int i = ((id - 4096) * 256 + tid) * 8;
    f32x4 a = *(const f32x4*)(x + i);
    f32x4 b = *(const f32x4*)(x + i + 4);
    u16x8 o;
#pragma unroll
    for (int j = 0; j < 4; ++j) { o[j] = f2bf(a[j]); o[j + 4] = f2bf(b[j]); }
    *(u16x8*)(xb + i) = o;
  }
}

// ---------- QKV GEMM: A[M][1024]*Bt[3072][1024]^T; Q->Qb, K->Kp, V->Vt ----------
__global__ __launch_bounds__(512) void k_gemm_qkv(const unsigned short* __restrict__ A,
                                                  const unsigned short* __restrict__ Bt,
                                                  unsigned short* __restrict__ Qb,
                                                  float ascale,
                                                  unsigned short* __restrict__ kp,
                                                  unsigned short* __restrict__ vt) {
  constexpr int K = DM, NS = K / 32;
  __shared__ alignas(16) unsigned short As[2][128 * 32];
  __shared__ alignas(16) unsigned short Bs[2][128 * 32];
  const int tid = threadIdx.x;
  const int m0 = blockIdx.y * 128, n0 = blockIdx.x * 128;
  const int lane = tid & 63, w = tid >> 6;
  const int lr = lane & 15, lg = lane >> 4;
  const int wm = w >> 2, wn = w & 3;  // 2 x 4 waves; per-wave region 64 x 32
  const int srow = tid >> 2, scc = (tid & 3) ^ ((srow >> 1) & 3);
  const unsigned short* Ab = A + (size_t)(m0 + srow) * K + scc * 8;
  const unsigned short* Bb = Bt + (size_t)(n0 + srow) * K + scc * 8;
  auto stage = [&](int buf, int s) {
    gld16(Ab + s * 32, (void*)(As[buf] + tid * 8));
    gld16(Bb + s * 32, (void*)(Bs[buf] + tid * 8));
  };
  f32x4 acc[4][2] = {};
  stage(0, 0);
  for (int s = 0; s < NS; ++s) {
    const int buf = s & 1;
    asm volatile("s_waitcnt vmcnt(0)" ::: "memory");
    __builtin_amdgcn_s_barrier();
    if (s + 1 < NS) stage(buf ^ 1, s + 1);  // overwrites buf read at s-1: safe
    bf16x8 af[4], bfr[2];
#pragma unroll
    for (int i = 0; i < 4; ++i) {
      const int row = wm * 64 + i * 16 + lr;
      af[i] = ldsb8(As[buf] + row * 32 + ((lg ^ ((row >> 1) & 3)) * 8));
    }
#pragma unroll
    for (int j = 0; j < 2; ++j) {
      const int row = wn * 32 + j * 16 + lr;
      bfr[j] = ldsb8(Bs[buf] + row * 32 + ((lg ^ ((row >> 1) & 3)) * 8));
    }
    __builtin_amdgcn_s_setprio(1);
#pragma unroll
    for (int i = 0; i < 4; ++i)
#pragma unroll
      for (int j = 0; j < 2; ++j)
        acc[i][j] = __builtin_amdgcn_mfma_f32_16x16x32_bf16(af[i], bfr[j], acc[i][j], 0, 0, 0);
    __builtin_amdgcn_s_setprio(0);
  }
#pragma unroll
  for (int i = 0; i < 4; ++i)
#pragma unroll
    for (int j = 0; j < 2; ++j) {
      const int row = m0 + wm * 64 + i * 16 + lg * 4;
      const int col = n0 + wn * 32 + j * 16 + lr;
      const int bb = row >> 11, sg = row & (TT - 1);
      if (col < DM) {  // Q (pre-scaled)
#pragma unroll
        for (int r = 0; r < 4; ++r)
          Qb[(size_t)(row + r) * DM + col] = f2bf(acc[i][j][r] * ascale);
      } else if (col < 2 * DM) {  // K -> packed swizzled tiles
        const int hh = (col - DM) >> 6, dd = (col - DM) & 63;
        unsigned short* kb = kp + (size_t)(bb * NH + hh) * 32 * 4096;
#pragma unroll
        for (int r = 0; r < 4; ++r) {
          const int s = sg + r, t = s >> 6, sl = s & 63;
          kb[t * 4096 + sl * 64 + (((dd >> 3) ^ (sl & 7)) * 8) + (dd & 7)] = f2bf(acc[i][j][r]);
        }
      } else {  // V -> PV-native tiles
        const int hh = (col - 2 * DM) >> 6, dd = (col - 2 * DM) & 63;
        const int t = sg >> 6, sl = sg & 63;
        const int g = ((sl >> 5) << 2) | ((sl >> 2) & 3);
        const int hf2 = (sl >> 4) & 1;
        const int cch = g ^ (dd & 7);
        u16x4 pk;
#pragma unroll
        for (int r = 0; r < 4; ++r) pk[r] = f2bf(acc[i][j][r]);
        *(u16x4*)(vt + (size_t)((bb * NH + hh) * 32 + t) * 4096 + dd * 64 + cch * 8 + hf2 * 4) = pk;
      }
    }
}

// ---------- out-proj GEMM: double-buffered, one barrier per K-step ----------
__global__ __launch_bounds__(512) void k_gemm_out(const unsigned short* __restrict__ A,
                                                  const unsigned short* __restrict__ Bt,
                                                  float* __restrict__ C) {
  constexpr int K = DM, N = DM, NS = K / 32;
  __shared__ alignas(16) unsigned short As[2][128 * 32];
  __shared__ alignas(16) unsigned short Bs[2][64 * 32];
  const int tid = threadIdx.x;
  const int m0 = blockIdx.y * 128, n0 = blockIdx.x * 64;
  const int lane = tid & 63, w = tid >> 6;
  const int lr = lane & 15, lg = lane >> 4;
  const int wm = w >> 1, wn = w & 1;
  const int srow = tid >> 2, scc = (tid & 3) ^ ((srow >> 1) & 3);
  const unsigned short* Ab = A + (size_t)(m0 + srow) * K + scc * 8;
  const unsigned short* Bb = (tid < 256) ? Bt + (size_t)(n0 + srow) * K + scc * 8 : nullptr;
  auto stage = [&](int buf, int s) {
    gld16(Ab + s * 32, (void*)(As[buf] + tid * 8));
    if (tid < 256) gld16(Bb + s * 32, (void*)(Bs[buf] + tid * 8));
  };
  f32x4 acc[2][2] = {};
  stage(0, 0);
  for (int s = 0; s < NS; ++s) {
    const int buf = s & 1;
    asm volatile("s_waitcnt vmcnt(0)" ::: "memory");
    __builtin_amdgcn_s_barrier();
    if (s + 1 < NS) stage(buf ^ 1, s + 1);
    bf16x8 af[2], bfr[2];
#pragma unroll
    for (int i = 0; i < 2; ++i) {
      const int row = wm * 32 + i * 16 + lr;
      af[i] = ldsb8(As[buf] + row * 32 + ((lg ^ ((row >> 1) & 3)) * 8));
    }
#pragma unroll
    for (int j = 0; j < 2; ++j) {
      const int row = wn * 32 + j * 16 + lr;
      bfr[j] = ldsb8(Bs[buf] + row * 32 + ((lg ^ ((row >> 1) & 3)) * 8));
    }
    __builtin_amdgcn_s_setprio(1);
#pragma unroll
    for (int i = 0; i < 2; ++i)
#pragma unroll
      for (int j = 0; j < 2; ++j)
        acc[i][j] = __builtin_amdgcn_mfma_f32_16x16x32_bf16(af[i], bfr[j], acc[i][j], 0, 0, 0);
    __builtin_amdgcn_s_setprio(0);
  }
#pragma unroll
  for (int i = 0; i < 2; ++i)
#pragma unroll
    for (int j = 0; j < 2; ++j) {
      const int row = m0 + wm * 32 + i * 16 + lg * 4;
      const int col = n0 + wn * 32 + j * 16 + lr;
#pragma unroll
      for (int r = 0; r < 4; ++r) C[(size_t)(row + r) * N + col] = acc[i][j][r];
    }
}

// ---------- causal flash attention v15: split-K triple-buffer + MFMA row-sum ----------
__constant__ const signed char JV[24]  = {15,7,14,14,13,13,12,11, 15,6,12,10,10,9,11,5, 0,1,2,3,8,4,8,9};
__constant__ const signed char T0v[24] = {0,0,0,15,0,14,13,12, 16,0,0,0,11,0,0,0, 0,0,0,0,0,0,9,10};
__constant__ const signed char CNTv[24]= {16,16,15,15,14,14,13,12, 16,14,13,11,11,10,12,12, 2,4,6,8,9,10,9,10};

__global__ __launch_bounds__(512) void k_attn15(const unsigned short* __restrict__ Qb,
                                                const unsigned short* __restrict__ Kp,
                                                const unsigned short* __restrict__ Vt,
                                                unsigned short* __restrict__ O,
                                                float* __restrict__ Oacc0,
                                                float* __restrict__ Oacc1,
                                                float* __restrict__ lacc0,
                                                float* __restrict__ lacc1) {
  __shared__ alignas(16) unsigned short Ks[3][64 * 64];
  __shared__ alignas(16) unsigned short Vs[3][64 * 64];
  const int id = blockIdx.x;
  const int rank = id >> 5, bh = id & 31;
  const int j = JV[rank], t0 = T0v[rank], cnt = CNTv[rank];
  const bool split = (j >= 8);
  const int hf = (t0 > 0) ? 1 : 0;
  const int b = bh >> 4, h = bh & 15;
  const int q0 = j * 128;
  const int tid = threadIdx.x, lane = tid & 63, w = tid >> 6;
  const int lr = lane & 15, lg = lane >> 4;
  const int lsw = lr & 7;
  const int qw = q0 + w * 16;
  const unsigned short* Qg = Qb + (size_t)b * TT * DM + h * DH;
  const unsigned short* kbase = Kp + (size_t)bh * 32 * 4096 + tid * 8;
  const unsigned short* vbase = Vt + (size_t)bh * 32 * 4096 + tid * 8;

  bf16x8 qf[2];
#pragma unroll
  for (int c2 = 0; c2 < 2; ++c2)
    qf[c2] = *(const bf16x8*)(Qg + (size_t)(qw + lr) * DM + c2 * 32 + lg * 8);

  bf16x8 onef;
  {
    union { unsigned short s[8]; bf16x8 v; } ou;
#pragma unroll
    for (int i = 0; i < 8; ++i) ou.s[i] = 0x3F80;
    onef = ou.v;
  }

  f32x4 acco[4] = {};
  f32x4 lac = {};  // lac[r] = running row-sum for q = qw + lg*4 + r (all lr equal)

  auto stage = [&](int buf, int t) {
    gld16(kbase + (size_t)t * 4096, (void*)(Ks[buf] + tid * 8));
    gld16(vbase + (size_t)t * 4096, (void*)(Vs[buf] + tid * 8));
  };

  stage(0, t0);
  stage(1, t0 + 1);  // cnt >= 2 always
  int buf = 0;
  for (int k = 0; k < cnt; ++k) {
    const int t = t0 + k;
    if (k + 1 < cnt) {
      asm volatile("s_waitcnt vmcnt(2)" ::: "memory");  // tile t landed; t+1 in flight
    } else {
      asm volatile("s_waitcnt vmcnt(0)" ::: "memory");
    }
    __builtin_amdgcn_s_barrier();
    if (k + 2 < cnt) {
      int nb = buf + 2; if (nb >= 3) nb -= 3;
      stage(nb, t + 2);  // targets buf read 2 iters ago; all waves done with it
    }
    const int s0 = t * 64;
    if (s0 <= qw + 15) {  // not fully masked for this wave
      const unsigned short* Kb_ = Ks[buf];
      const unsigned short* Vb_ = Vs[buf];
      // ---- S^T = K Q^T (exp2 domain; Q pre-scaled) ----
      f32x4 st[4] = {};
      __builtin_amdgcn_s_setprio(1);
#pragma unroll
      for (int ct = 0; ct < 4; ++ct)
#pragma unroll
        for (int c2 = 0; c2 < 2; ++c2) {
          bf16x8 kf = ldsb8(Kb_ + (ct * 16 + lr) * 64 + (((c2 * 4 + lg) ^ lsw) * 8));
          st[ct] = __builtin_amdgcn_mfma_f32_16x16x32_bf16(kf, qf[c2], st[ct], 0, 0, 0);
        }
      __builtin_amdgcn_s_setprio(0);
      // ---- max-free softmax: p = exp2(s2); masked -> 0 ----
      float p[4][4];
      const int qrel = qw + lr - s0;
      if (s0 + 63 >= qw) {  // diagonal tile
#pragma unroll
        for (int ct = 0; ct < 4; ++ct)
#pragma unroll
          for (int r = 0; r < 4; ++r) {
            float v = st[ct][r];
            if (ct * 16 + lg * 4 + r > qrel) v = -1e30f;
            p[ct][r] = v;
          }
      } else {
#pragma unroll
        for (int ct = 0; ct < 4; ++ct)
#pragma unroll
          for (int r = 0; r < 4; ++r) p[ct][r] = st[ct][r];
      }
#pragma unroll
      for (int ct = 0; ct < 4; ++ct)
#pragma unroll
        for (int r = 0; r < 4; ++r) p[ct][r] = __builtin_exp2f(p[ct][r]);
      // ---- P in registers (custom k-map A-fragments) ----
      bf16x8 pf[2];
#pragma unroll
      for (int ks = 0; ks < 2; ++ks) {
        union { unsigned w4[4]; bf16x8 v; } pu;
        pu.w4[0] = cvtpk(p[2 * ks][0], p[2 * ks][1]);
        pu.w4[1] = cvtpk(p[2 * ks][2], p[2 * ks][3]);
        pu.w4[2] = cvtpk(p[2 * ks + 1][0], p[2 * ks + 1][1]);
        pu.w4[3] = cvtpk(p[2 * ks + 1][2], p[2 * ks + 1][3]);
        pf[ks] = pu.v;
      }
      // ---- O += P V^T, and l += P @ 1 on the matrix pipe ----
      __builtin_amdgcn_s_setprio(1);
#pragma unroll
      for (int dt = 0; dt < 4; ++dt) {
        const unsigned short* Vrow = Vb_ + (dt * 16 + lr) * 64;
#pragma unroll
        for (int ks = 0; ks < 2; ++ks) {
          bf16x8 vf = ldsb8(Vrow + (((ks * 4 + lg) ^ lsw) * 8));
          acco[dt] = __builtin_amdgcn_mfma_f32_16x16x32_bf16(pf[ks], vf, acco[dt], 0, 0, 0);
        }
      }
#pragma unroll
      for (int ks = 0; ks < 2; ++ks)
        lac = __builtin_amdgcn_mfma_f32_16x16x32_bf16(pf[ks], onef, lac, 0, 0, 0);
      __builtin_amdgcn_s_setprio(0);
    }
    if (++buf >= 3) buf = 0;
  }
  // ---- epilogue: lac[r] is l[q] replicated across lr -> no shuffles ----
  if (!split) {
#pragma unroll
    for (int r = 0; r < 4; ++r) {
      const float linv = 1.f / lac[r];
      const int q = qw + lg * 4 + r;
#pragma unroll
      for (int dt = 0; dt < 4; ++dt)
        O[(size_t)(b * TT + q) * DM + h * DH + dt * 16 + lr] = f2bf(acco[dt][r] * linv);
    }
  } else {
    const int jj = j - 8;
    float* Oa = (hf ? Oacc1 : Oacc0) + (size_t)(bh * 8 + jj) * 128 * 64;
    float* la = (hf ? lacc1 : lacc0) + (size_t)(bh * 8 + jj) * 128;
#pragma unroll
    for (int dt = 0; dt < 4; ++dt)
#pragma unroll
      for (int r = 0; r < 4; ++r)
        Oa[(w * 16 + lg * 4 + r) * 64 + dt * 16 + lr] = acco[dt][r];
    if (lr == 0) {
#pragma unroll
      for (int r = 0; r < 4; ++r) la[w * 16 + lg * 4 + r] = lac[r];
    }
  }
}

// ---------- merge+normalize for split tiles (j>=8: q in [1024,2048) per b) ----------
__global__ __launch_bounds__(256) void k_norm(const float* __restrict__ Oacc0,
                                              const float* __restrict__ Oacc1,
                                              const float* __restrict__ lacc0,
                                              const float* __restrict__ lacc1,
                                              unsigned short* __restrict__ O) {
  const int gid = blockIdx.x * 256 + threadIdx.x;
  const int f = gid * 8;
  const int d0 = f & 63, row = (f >> 6) & 127, jj = (f >> 13) & 7, bh = f >> 16;
  const int b = bh >> 4, h = bh & 15;
  const size_t ri = (size_t)(bh * 8 + jj) * 128 + row;
  const size_t oi = ri * 64 + d0;
  f32x4 a0 = *(const f32x4*)(Oacc0 + oi);
  f32x4 a1 = *(const f32x4*)(Oacc0 + oi + 4);
  f32x4 b0 = *(const f32x4*)(Oacc1 + oi);
  f32x4 b1 = *(const f32x4*)(Oacc1 + oi + 4);
  const float linv = 1.f / (lacc0[ri] + lacc1[ri]);
  u16x8 o;
#pragma unroll
  for (int r = 0; r < 4; ++r) {
    o[r] = f2bf((a0[r] + b0[r]) * linv);
    o[r + 4] = f2bf((a1[r] + b1[r]) * linv);
  }
  const int q = 1024 + jj * 128 + row;
  *(u16x8*)(O + (size_t)(b * TT + q) * DM + h * DH + d0) = o;
}

extern "C" void kernel_launch(void* const* d_in, const int* in_sizes, int n_in,
                              void* d_out, int out_size, void* d_ws, size_t ws_size,
                              hipStream_t stream) {
  const float* x = (const float*)d_in[0];
  const float* wq = (const float*)d_in[1];
  const float* wk = (const float*)d_in[2];
  const float* wv = (const float*)d_in[3];
  const float* wo = (const float*)d_in[4];
  float* out = (float*)d_out;
  char* ws = (char*)d_ws;
  const size_t MB = 1u << 20;
  // ws layout (48 MB), lifetime-disjoint reuse:
  unsigned short* xb = (unsigned short*)(ws);              // 8MB: x bf16 (dead after qkv)
  float* Oacc0 = (float*)(ws);                             //  ... reused: fp32 O partials h=0
  unsigned short* wqt = (unsigned short*)(ws + 8 * MB);    // 8MB: 4 transposed weights
  float* lacc0 = (float*)(ws + 8 * MB);                    //  ... wq^T dead after qkv: l partials
  float* lacc1 = (float*)(ws + 8 * MB + (32 * 8 * 128) * 4);
  unsigned short* wot = (unsigned short*)(ws + 14 * MB);   // wo^T (live until out-proj)
  unsigned short* Qb = (unsigned short*)(ws + 16 * MB);    // 8MB: Q; reused as attn-out
  unsigned short* Kp = (unsigned short*)(ws + 24 * MB);    // 8MB: packed swizzled K tiles
  unsigned short* Vtb = (unsigned short*)(ws + 32 * MB);   // 8MB: PV-native V tiles
  float* Oacc1 = (float*)(ws + 40 * MB);                   // 8MB: fp32 O partials h=1

  k_prep<<<dim3(6144), 256, 0, stream>>>(x, wq, wk, wv, wo, xb, wqt);
  k_gemm_qkv<<<dim3(24, 32), 512, 0, stream>>>(xb, wqt, Qb, 0.18033688f, Kp, Vtb);
  k_attn15<<<dim3(768), 512, 0, stream>>>(Qb, Kp, Vtb, Qb, Oacc0, Oacc1, lacc0, lacc1);
  k_norm<<<dim3(1024), 256, 0, stream>>>(Oacc0, Oacc1, lacc0, lacc1, Qb);
  k_gemm_out<<<dim3(16, 32), 512, 0, stream>>>(Qb, wot, out);
}